// Round 7
// baseline (600.372 us; speedup 1.0000x reference)
//
#include <hip/hip_runtime.h>
#include <hip/hip_bf16.h>
#include <stdint.h>

// RecNN: B=2048, L=256, F=64, H=128. One WG (512 thr, 8 waves) per 8 batch
// elems. Subtree-BFS(16 leaves) + DFS over 16 roots. Waves = 4 col-groups x
// 2 M-groups; each wave owns 32 output cols (2 nt frags), one A-read feeds
// 2 MFMAs. Second nt's weights+acc live in AGPRs via inline-asm MFMA.
// HAZARD HARDENING (round-6 post-mortem: absmax 4.3 from missing MFMA wait
// states around opaque asm): s_nop 2 prefix in every asm MFMA; chain start
// uses SrcC=0 literal (no accvgpr_write init); s_nop 7 x2 fence (data-chained)
// before reading AGPR accumulators; pad A-frags come from an LDS zero row
// (ds_read, never VALU-written).

#define B_TOT 2048
#define LL    256
#define FF    64
#define HH    128
#define LF    (LL*FF)
#define BC    8
#define NTHR  512
#define NSUB  16

typedef __bf16    v8bf __attribute__((ext_vector_type(8)));
typedef float     v4f  __attribute__((ext_vector_type(4)));
typedef uint32_t  v4u  __attribute__((ext_vector_type(4)));

// ---- LDS layout (bytes) ----
#define XB_OFF    0        // [128]x128B bf16 swz128: leaf x            16384
#define XB2_OFF   16384    // [128]x128B bf16 swz128: data1..4 + root   16384
#define DB_OFF    32768    // [64]x256B f32 swz256: data1 / data3       16384
#define DB2_OFF   49152    // [48]x256B f32 swz256: data2 / data4       12288
#define HA_OFF    61440    // [128]x256B bf16 swz256: h0 / h2           32768
#define HB_OFF    94208    // [64]x256B bf16: h1 / h3 / z2              16384
#define U_OFF     110592   // [64]x256B bf16: u / z1                    16384
#define HCUR_OFF  126976   // [16]x256B bf16: root h                     4096
#define DCUR_OFF  131072   // [8]x256B f32: root data                    2048
#define HSTK_OFF  133120   // 4 x 4096                                  16384
#define DSTK_OFF  149504   // 4 x 2048                                   8192
#define BIAS_OFF  157696   // 4 x 512B f32                               2048
#define ZR_OFF    159744   // 256B zero row (pad A-frags)                 256
#define LDS_BYTES 160000

__device__ __forceinline__ uint32_t swz256(uint32_t row, uint32_t b){
    return (row*256u + b) ^ ((row & 7u) << 4);
}
__device__ __forceinline__ uint32_t swz128(uint32_t row, uint32_t b){
    return (row*128u + b) ^ ((row & 7u) << 4);
}
__device__ __forceinline__ v4f mfma16(v8bf a, v8bf b, v4f c){
    return __builtin_amdgcn_mfma_f32_16x16x32_bf16(a, b, c, 0, 0, 0);
}
// AGPR-path MFMA, accumulate: D/C and B in AGPRs, A in VGPRs.
// s_nop 2 guards any VALU-write -> MFMA-src hazard (compiler won't around asm).
__device__ __forceinline__ void mfma16_ab(v8bf a, v4u b, v4f& c){
    v4u av = __builtin_bit_cast(v4u, a);
    asm("s_nop 2\n\tv_mfma_f32_16x16x32_bf16 %0, %1, %2, %0"
        : "+a"(c) : "v"(av), "a"(b));
}
// AGPR-path MFMA, chain start: SrcC = inline 0 (no accvgpr_write init chain).
__device__ __forceinline__ void mfma16_ab_first(v8bf a, v4u b, v4f& c){
    v4u av = __builtin_bit_cast(v4u, a);
    asm("s_nop 2\n\tv_mfma_f32_16x16x32_bf16 %0, %1, %2, 0"
        : "=a"(c) : "v"(av), "a"(b));
}
// 16 stall cycles between last MFMA write and first read of the accumulator.
__device__ __forceinline__ void agpr_fence(v4f& c){
    asm("s_nop 7\n\ts_nop 7" : "+a"(c));
}
__device__ __forceinline__ uint32_t pk2(float a, float b){
    uint32_t lo = (uint32_t)__builtin_bit_cast(unsigned short, (__bf16)a);
    uint32_t hi = (uint32_t)__builtin_bit_cast(unsigned short, (__bf16)b);
    return lo | (hi << 16);
}
__device__ __forceinline__ uint2 pk4(v4f v){
    return make_uint2(pk2(v[0], v[1]), pk2(v[2], v[3]));
}

// B-fragment: lane holds col n0+(l&15), k = k0 + 8*(l>>4) + j. W row-major [K][128] f32.
__device__ __forceinline__ v8bf ldW(const float* __restrict__ W, int k0, int n0){
    uint32_t lane = threadIdx.x & 63u;
    int n = n0 + (int)(lane & 15u);
    int k = k0 + (int)((lane >> 4) << 3);
    v8bf r;
    #pragma unroll
    for (int j = 0; j < 8; ++j) r[j] = (__bf16)W[(k + j)*HH + n];
    return r;
}

// A-frag from bf16 64-col panel (swz128). rows >= realrows -> zero row (ds_read).
__device__ __forceinline__ v8bf ldX(const char* xb, const char* zr, uint32_t row0,
                                    uint32_t mt, uint32_t kf, uint32_t realrows){
    uint32_t lane = threadIdx.x & 63u;
    uint32_t rl = mt*16u + (lane & 15u);
    if (rl >= realrows)
        return *reinterpret_cast<const v8bf*>(zr + ((lane & 15u) << 4));
    return *reinterpret_cast<const v8bf*>(xb + swz128(row0 + rl, kf*64u + ((lane>>4)<<4)));
}

// A-frag from 16-row bf16 buffer (swz256), row = lane&15 (merge/head GEMMs)
__device__ __forceinline__ v8bf ldH(const char* buf, uint32_t kf){
    uint32_t lane = threadIdx.x & 63u;
    return *reinterpret_cast<const v8bf*>(buf + swz256(lane & 15u,
                                          kf*64u + ((lane>>4)<<4)));
}

// A-frag for subtree nl GEMM (node-major): out tile mt -> nodes 2mt,2mt+1;
// children rows 32mt+16*(r>=8)+8*sec+(r&7); u row 16mt+r.
__device__ __forceinline__ v8bf ldA_nl(const char* hprev, const char* ub,
                                       uint32_t mt, uint32_t kf){
    uint32_t lane = threadIdx.x & 63u, r = lane & 15u;
    uint32_t kb = (kf & 3u)*64u + ((lane >> 4) << 4);
    uint32_t sec = kf >> 2;
    if (sec < 2u){
        uint32_t row = mt*32u + ((r >> 3) << 4) + sec*8u + (r & 7u);
        return *reinterpret_cast<const v8bf*>(hprev + swz256(row, kb));
    }
    return *reinterpret_cast<const v8bf*>(ub + swz256(mt*16u + r, kb));
}

// Epilogue: relu(acc+bias) -> bf16 swz256 LDS at rows row0+(l>>4)*4+r, col 16nt+(l&15)
__device__ __forceinline__ void epi(char* dst, uint32_t row0, v4f acc, int nt,
                                    const float* bias){
    uint32_t lane = threadIdx.x & 63u;
    uint32_t col = (uint32_t)nt*16u + (lane & 15u);
    float bv = bias[col];
    uint32_t r0 = row0 + ((lane >> 4) << 2);
    #pragma unroll
    for (int r = 0; r < 4; ++r){
        float v = fmaxf(acc[r] + bv, 0.f);
        *reinterpret_cast<__bf16*>(dst + swz256(r0 + r, col*2u)) = (__bf16)v;
    }
}

// data/leaf GEMM: relu(A @ Wleaf + b); nt0 via builtin (VGPR W), nt0+1 via AGPR W
template<int MTN>
__device__ __forceinline__ void gemm_x2(const char* xb, const char* zr, uint32_t row0,
                                        uint32_t realrows, char* dst, uint32_t mtB,
                                        const v8bf (&wV)[2], const v4u (&wA)[2],
                                        int nt0, const float* bias){
    v4f accV[MTN], accA[MTN];
    {
        v8bf a[MTN];
        #pragma unroll
        for (int i = 0; i < MTN; ++i) a[i] = ldX(xb, zr, row0, mtB + i, 0, realrows);
        #pragma unroll
        for (int i = 0; i < MTN; ++i){
            accV[i] = mfma16(a[i], wV[0], (v4f){0,0,0,0});
            mfma16_ab_first(a[i], wA[0], accA[i]);
        }
    }
    {
        v8bf a[MTN];
        #pragma unroll
        for (int i = 0; i < MTN; ++i) a[i] = ldX(xb, zr, row0, mtB + i, 1, realrows);
        #pragma unroll
        for (int i = 0; i < MTN; ++i){
            accV[i] = mfma16(a[i], wV[1], accV[i]);
            mfma16_ab(a[i], wA[1], accA[i]);
        }
    }
    #pragma unroll
    for (int i = 0; i < MTN; ++i){
        epi(dst, (mtB + i)*16u, accV[i], nt0, bias);
        agpr_fence(accA[i]);
        epi(dst, (mtB + i)*16u, accA[i], nt0 + 1, bias);
    }
}

// nl GEMM: relu([h_even|h_odd|u] @ Wnl + b), node-major, 2 nt per wave
template<int MTN>
__device__ __forceinline__ void gemm_nl2(const char* hprev, const char* ub, char* dst,
                                         uint32_t mtB, const v8bf (&wV)[12],
                                         const v4u (&wA)[12], int nt0, const float* bias){
    v4f accV[MTN], accA[MTN];
    {
        v8bf a[MTN];
        #pragma unroll
        for (int i = 0; i < MTN; ++i) a[i] = ldA_nl(hprev, ub, mtB + i, 0);
        #pragma unroll
        for (int i = 0; i < MTN; ++i){
            accV[i] = mfma16(a[i], wV[0], (v4f){0,0,0,0});
            mfma16_ab_first(a[i], wA[0], accA[i]);
        }
    }
    #pragma unroll
    for (uint32_t kf = 1; kf < 12; ++kf){
        v8bf a[MTN];
        #pragma unroll
        for (int i = 0; i < MTN; ++i) a[i] = ldA_nl(hprev, ub, mtB + i, kf);
        #pragma unroll
        for (int i = 0; i < MTN; ++i){
            accV[i] = mfma16(a[i], wV[kf], accV[i]);
            mfma16_ab(a[i], wA[kf], accA[i]);
        }
    }
    #pragma unroll
    for (int i = 0; i < MTN; ++i){
        epi(dst, (mtB + i)*16u, accV[i], nt0, bias);
        agpr_fence(accA[i]);
        epi(dst, (mtB + i)*16u, accA[i], nt0 + 1, bias);
    }
}

__global__ __launch_bounds__(NTHR)
__attribute__((amdgpu_waves_per_eu(2, 2)))
void recnn_kernel(const float* __restrict__ Xg,
                  const float* __restrict__ Wleaf, const float* __restrict__ bleaf,
                  const float* __restrict__ Wnl,   const float* __restrict__ bnl,
                  const float* __restrict__ W1g,   const float* __restrict__ b1g,
                  const float* __restrict__ W2g,   const float* __restrict__ b2g,
                  const float* __restrict__ W3g,   const float* __restrict__ b3g,
                  float* __restrict__ Yg)
{
    __shared__ __align__(16) char lds[LDS_BYTES];
    const int t    = threadIdx.x;
    const int wave = t >> 6;
    const int wn   = wave & 3;     // column group: cols [32wn, 32wn+32)
    const int wm   = wave >> 2;    // M group / nt-split role
    const int base = blockIdx.x * BC;

    char*  XB   = lds + XB_OFF;
    char*  XB2  = lds + XB2_OFF;
    char*  DB   = lds + DB_OFF;
    char*  DB2  = lds + DB2_OFF;
    char*  HA   = lds + HA_OFF;
    char*  HB   = lds + HB_OFF;
    char*  Ub   = lds + U_OFF;
    char*  HCUR = lds + HCUR_OFF;
    char*  DCUR = lds + DCUR_OFF;
    char*  HSTK = lds + HSTK_OFF;
    char*  DSTK = lds + DSTK_OFF;
    char*  ZR   = lds + ZR_OFF;
    float* BL   = (float*)(lds + BIAS_OFF);
    float* BN   = BL + 128;
    float* B1L  = BL + 256;
    float* B2L  = BL + 384;

    if (t < 128){
        BL[t]  = bleaf[t];
        BN[t]  = bnl[t];
        B1L[t] = b1g[t];
        B2L[t] = b2g[t];
    }
    if (t < 16) *reinterpret_cast<v4f*>(ZR + t*16) = (v4f){0,0,0,0};

    // Persistent weights: nt0 = 2wn in VGPRs (builtin path), nt0+1 in AGPRs (asm path)
    const int nt0 = wn * 2;
    const int nt_eff = nt0 + wm;   // for nt-split small phases
    v8bf wlfV[2], wnlV[12];
    v4u  wlfA[2], wnlA[12];
    #pragma unroll
    for (int kf = 0; kf < 2; ++kf){
        wlfV[kf] = ldW(Wleaf, kf*32, nt0*16);
        wlfA[kf] = __builtin_bit_cast(v4u, ldW(Wleaf, kf*32, nt0*16 + 16));
    }
    #pragma unroll
    for (int kf = 0; kf < 12; ++kf){
        wnlV[kf] = ldW(Wnl, kf*32, nt0*16);
        wnlA[kf] = __builtin_bit_cast(v4u, ldW(Wnl, kf*32, nt0*16 + 16));
    }

    // fused pairwise sum: srcF(swz256,node-major) -> dstF f32 + XB2 bf16 mirror
    auto sum_level = [&](char* dstF, uint32_t dRow0, uint32_t xRow0,
                         const char* srcF, uint32_t sRow0, int outrows){
        int total = outrows * 16;
        for (int idx = t; idx < total; idx += NTHR){
            uint32_t row = (uint32_t)(idx >> 4), q = (uint32_t)(idx & 15);
            uint32_t n = row >> 3, b = row & 7u;
            v4f a = *reinterpret_cast<const v4f*>(srcF + swz256(sRow0 + n*16u + b,      q*16u));
            v4f c = *reinterpret_cast<const v4f*>(srcF + swz256(sRow0 + n*16u + 8u + b, q*16u));
            v4f sv = a + c;
            *reinterpret_cast<v4f*>(dstF + swz256(dRow0 + row, q*16u)) = sv;
            *reinterpret_cast<uint2*>(XB2 + swz128(xRow0 + row, q*8u)) = pk4(sv);
        }
    };
    // small (M<=16) u-GEMM, nt-split: wm=0 -> VGPR weights, wm=1 -> AGPR weights
    auto small_u = [&](uint32_t row0, uint32_t realrows){
        v4f c;
        if (wm == 0){
            c = mfma16(ldX(XB2, ZR, row0, 0, 0, realrows), wlfV[0], (v4f){0,0,0,0});
            c = mfma16(ldX(XB2, ZR, row0, 0, 1, realrows), wlfV[1], c);
        } else {
            mfma16_ab_first(ldX(XB2, ZR, row0, 0, 0, realrows), wlfA[0], c);
            mfma16_ab(ldX(XB2, ZR, row0, 0, 1, realrows), wlfA[1], c);
            agpr_fence(c);
        }
        epi(Ub, 0, c, nt_eff, BL);
    };
    // small nl-GEMM (M=16 tile), nt-split
    auto small_nl = [&](const char* hprev, char* dst){
        v4f c;
        if (wm == 0){
            c = mfma16(ldA_nl(hprev, Ub, 0, 0), wnlV[0], (v4f){0,0,0,0});
            #pragma unroll
            for (uint32_t kf = 1; kf < 12; ++kf)
                c = mfma16(ldA_nl(hprev, Ub, 0, kf), wnlV[kf], c);
        } else {
            mfma16_ab_first(ldA_nl(hprev, Ub, 0, 0), wnlA[0], c);
            #pragma unroll
            for (uint32_t kf = 1; kf < 12; ++kf)
                mfma16_ab(ldA_nl(hprev, Ub, 0, kf), wnlA[kf], c);
            agpr_fence(c);
        }
        epi(dst, 0, c, nt_eff, BN);
    };

    int sp = 0;
    for (int s = 0; s < NSUB; ++s){
        // push previous root
        if (s > 0){
            ((uint2*)(HSTK + sp*4096))[t]    = ((const uint2*)HCUR)[t];
            ((uint32_t*)(DSTK + sp*2048))[t] = ((const uint32_t*)DCUR)[t];
            ++sp;
        }
        // stage: x -> XB bf16; data1 -> DB f32 + XB2[0:64) bf16
        #pragma unroll
        for (int k = 0; k < 2; ++k){
            int idx = t + k*NTHR;                  // 0..1023
            uint32_t rp = (uint32_t)(idx >> 4), q = (uint32_t)(idx & 15);
            uint32_t n = rp >> 3, b = rp & 7u;
            const float* gp = Xg + (size_t)(base + b)*LF + (size_t)(s*16 + 2*n)*FF + q*4;
            v4f xA = *reinterpret_cast<const v4f*>(gp);
            v4f xC = *reinterpret_cast<const v4f*>(gp + FF);
            uint32_t rowA = n*16u + b;
            *reinterpret_cast<uint2*>(XB + swz128(rowA,      q*8u)) = pk4(xA);
            *reinterpret_cast<uint2*>(XB + swz128(rowA + 8u, q*8u)) = pk4(xC);
            v4f sv = xA + xC;
            *reinterpret_cast<v4f*>(DB + swz256(rp, q*16u)) = sv;
            *reinterpret_cast<uint2*>(XB2 + swz128(rp, q*8u)) = pk4(sv);
        }
        __syncthreads();

        // P1: leaf M=128 -> HA ; data2 -> DB2[0:32) + XB2[64:96)
        gemm_x2<2>(XB, ZR, 0, 128, HA, (uint32_t)(wm*4),     wlfV, wlfA, nt0, BL);
        gemm_x2<2>(XB, ZR, 0, 128, HA, (uint32_t)(wm*4 + 2), wlfV, wlfA, nt0, BL);
        sum_level(DB2, 0, 64, DB, 0, 32);
        __syncthreads();
        // P2: u1 M=64 -> U ; data3 -> DB[0:16) + XB2[96:112)
        gemm_x2<2>(XB2, ZR, 0, 64, Ub, (uint32_t)(wm*2), wlfV, wlfA, nt0, BL);
        sum_level(DB, 0, 96, DB2, 0, 16);
        __syncthreads();
        // P3: nl1 M=64 -> HB ; data4 -> DB2[32:40) + XB2[112:120)
        gemm_nl2<2>(HA, Ub, HB, (uint32_t)(wm*2), wnlV, wnlA, nt0, BN);
        sum_level(DB2, 32, 112, DB, 0, 8);
        __syncthreads();
        // P4: u2 M=32 -> U
        gemm_x2<1>(XB2, ZR, 64, 32, Ub, (uint32_t)wm, wlfV, wlfA, nt0, BL);
        __syncthreads();
        // P5: nl2 M=32 -> HA[0:32)
        gemm_nl2<1>(HB, Ub, HA, (uint32_t)wm, wnlV, wnlA, nt0, BN);
        __syncthreads();
        // P6: u3 M=16 -> U (nt-split)
        small_u(96, 16);
        __syncthreads();
        // P7: nl3 M=16 -> HB[0:16) (nt-split)
        small_nl(HA, HB);
        __syncthreads();
        // P8: u4 M=8 -> U (nt-split)
        small_u(112, 8);
        __syncthreads();
        // P9: nl4 -> HCUR ; copy data4 f32 -> DCUR
        small_nl(HB, HCUR);
        {
            uint32_t row = (uint32_t)(t >> 6), f = (uint32_t)(t & 63);
            *reinterpret_cast<float*>(DCUR + swz256(row, f*4u)) =
                *reinterpret_cast<const float*>(DB2 + swz256(32u + row, f*4u));
        }
        __syncthreads();

        // DFS merges among subtree roots (M=8, nt-split)
        int nm = __builtin_ctz(s + 1);
        for (int m = 0; m < nm; ++m){
            --sp;
            const char* hl = HSTK + sp*4096;
            {   // root data sum + bf16 mirror -> XB2[120:128)
                uint32_t row = (uint32_t)(t >> 6), f = (uint32_t)(t & 63);
                float v = *reinterpret_cast<const float*>(DCUR + swz256(row, f*4u))
                        + *reinterpret_cast<const float*>(DSTK + sp*2048 + swz256(row, f*4u));
                *reinterpret_cast<float*>(DCUR + swz256(row, f*4u)) = v;
                *reinterpret_cast<__bf16*>(XB2 + swz128(120u + row, f*2u)) = (__bf16)v;
            }
            __syncthreads();
            small_u(120, 8);
            __syncthreads();
            v4f c;
            if (wm == 0){
                c = mfma16(ldH(hl, 0), wnlV[0], (v4f){0,0,0,0});
                #pragma unroll
                for (uint32_t kf = 1; kf < 12; ++kf){
                    const char* src = (kf < 4) ? hl : ((kf < 8) ? (const char*)HCUR
                                                                : (const char*)Ub);
                    c = mfma16(ldH(src, kf & 3u), wnlV[kf], c);
                }
            } else {
                mfma16_ab_first(ldH(hl, 0), wnlA[0], c);
                #pragma unroll
                for (uint32_t kf = 1; kf < 12; ++kf){
                    const char* src = (kf < 4) ? hl : ((kf < 8) ? (const char*)HCUR
                                                                : (const char*)Ub);
                    mfma16_ab(ldH(src, kf & 3u), wnlA[kf], c);
                }
                agpr_fence(c);
            }
            __syncthreads();   // reads of HCUR done before in-place write
            epi(HCUR, 0, c, nt_eff, BN);
            __syncthreads();
        }
    }

    // ---- head (nt-split, fresh VGPR weights): z1 -> U; z2 -> HB; out = z2@W3+b3 ----
    {
        v8bf w1f[4], w2f[4];
        #pragma unroll
        for (int kf = 0; kf < 4; ++kf){
            w1f[kf] = ldW(W1g, kf*32, nt_eff*16);
            w2f[kf] = ldW(W2g, kf*32, nt_eff*16);
        }
        {
            v4f c = (v4f){0,0,0,0};
            #pragma unroll
            for (uint32_t kf = 0; kf < 4; ++kf) c = mfma16(ldH(HCUR, kf), w1f[kf], c);
            epi(Ub, 0, c, nt_eff, B1L);
        }
        __syncthreads();
        {
            v4f c = (v4f){0,0,0,0};
            #pragma unroll
            for (uint32_t kf = 0; kf < 4; ++kf) c = mfma16(ldH(Ub, kf), w2f[kf], c);
            epi(HB, 0, c, nt_eff, B2L);
        }
        __syncthreads();
        if (t < 64){
            float w3a = W3g[t], w3b = W3g[t + 64], b3v = b3g[0];
            #pragma unroll
            for (int r = 0; r < 8; ++r){
                float za = (float)*reinterpret_cast<const __bf16*>(HB + swz256((uint32_t)r, (uint32_t)t*2u));
                float zb = (float)*reinterpret_cast<const __bf16*>(HB + swz256((uint32_t)r, (uint32_t)(t + 64)*2u));
                float v = za*w3a + zb*w3b;
                #pragma unroll
                for (int off = 32; off >= 1; off >>= 1) v += __shfl_xor(v, off, 64);
                if (t == 0) Yg[base + r] = v + b3v;
            }
        }
    }
}

extern "C" void kernel_launch(void* const* d_in, const int* in_sizes, int n_in,
                              void* d_out, int out_size, void* d_ws, size_t ws_size,
                              hipStream_t stream){
    const float* x     = (const float*)d_in[0];
    const float* Wleaf = (const float*)d_in[1];
    const float* bleaf = (const float*)d_in[2];
    const float* Wnl   = (const float*)d_in[3];
    const float* bnl   = (const float*)d_in[4];
    const float* W1    = (const float*)d_in[5];
    const float* b1    = (const float*)d_in[6];
    const float* W2    = (const float*)d_in[7];
    const float* b2    = (const float*)d_in[8];
    const float* W3    = (const float*)d_in[9];
    const float* b3    = (const float*)d_in[10];
    float* out = (float*)d_out;

    recnn_kernel<<<B_TOT/BC, NTHR, 0, stream>>>(x, Wleaf, bleaf, Wnl, bnl,
                                                W1, b1, W2, b2, W3, b3, out);
}

// Round 8
// 129.424 us; speedup vs baseline: 4.6388x; 4.6388x over previous
//
#include <hip/hip_runtime.h>
#include <hip/hip_bf16.h>
#include <stdint.h>

// RecNN: B=2048, L=256, F=64, H=128. One WG (512 thr, 8 waves) per 8 batch
// elems. Subtree-BFS(16 leaves) + DFS over 16 roots. Each wave owns ONE
// 16-col output tile (nt=wave): 56 persistent weight VGPRs — the proven
// no-spill budget (round 4). Data levels mirrored to bf16 panels at write
// time (round 5's verified dataflow): every GEMM A-read is a single
// ds_read_b128, no f32->bf16 cvt on the critical path.
// Round 6/7 lesson: inline-asm "a"-constraint AGPR residency doesn't work
// (compiler shuttles v<->a around every asm); stay within arch VGPRs.

#define B_TOT 2048
#define LL    256
#define FF    64
#define HH    128
#define LF    (LL*FF)
#define BC    8
#define NTHR  512
#define NSUB  16

typedef __bf16 v8bf __attribute__((ext_vector_type(8)));
typedef float  v4f  __attribute__((ext_vector_type(4)));

// ---- LDS layout (bytes) ----
#define XB_OFF    0        // [128]x128B bf16 swz128: leaf x            16384
#define XB2_OFF   16384    // [128]x128B bf16 swz128: data1..4 + root   16384
#define DB_OFF    32768    // [64]x256B f32 swz256: data1 / data3       16384
#define DB2_OFF   49152    // [48]x256B f32 swz256: data2 / data4       12288
#define HA_OFF    61440    // [128]x256B bf16 swz256: h0 / h2           32768
#define HB_OFF    94208    // [64]x256B bf16: h1 / h3 / z2              16384
#define U_OFF     110592   // [64]x256B bf16: u / z1                    16384
#define HCUR_OFF  126976   // [16]x256B bf16: root h                     4096
#define DCUR_OFF  131072   // [8]x256B f32: root data                    2048
#define HSTK_OFF  133120   // 4 x 4096                                  16384
#define DSTK_OFF  149504   // 4 x 2048                                   8192
#define BIAS_OFF  157696   // 4 x 512B f32                               2048
#define LDS_BYTES 159744

__device__ __forceinline__ uint32_t swz256(uint32_t row, uint32_t b){
    return (row*256u + b) ^ ((row & 7u) << 4);
}
__device__ __forceinline__ uint32_t swz128(uint32_t row, uint32_t b){
    return (row*128u + b) ^ ((row & 7u) << 4);
}
__device__ __forceinline__ v4f mfma16(v8bf a, v8bf b, v4f c){
    return __builtin_amdgcn_mfma_f32_16x16x32_bf16(a, b, c, 0, 0, 0);
}
__device__ __forceinline__ uint32_t pk2(float a, float b){
    uint32_t lo = (uint32_t)__builtin_bit_cast(unsigned short, (__bf16)a);
    uint32_t hi = (uint32_t)__builtin_bit_cast(unsigned short, (__bf16)b);
    return lo | (hi << 16);
}
__device__ __forceinline__ uint2 pk4(v4f v){
    return make_uint2(pk2(v[0], v[1]), pk2(v[2], v[3]));
}

// B-fragment: lane holds col n0+(l&15), k = k0 + 8*(l>>4) + j. W row-major [K][128] f32.
__device__ __forceinline__ v8bf ldW(const float* __restrict__ W, int k0, int n0){
    uint32_t lane = threadIdx.x & 63u;
    int n = n0 + (int)(lane & 15u);
    int k = k0 + (int)((lane >> 4) << 3);
    v8bf r;
    #pragma unroll
    for (int j = 0; j < 8; ++j) r[j] = (__bf16)W[(k + j)*HH + n];
    return r;
}

// A-frag from bf16 64-col panel (swz128). rows >= realrows -> 0.
__device__ __forceinline__ v8bf ldX(const char* xb, uint32_t row0, uint32_t mt,
                                    uint32_t kf, uint32_t realrows){
    uint32_t lane = threadIdx.x & 63u;
    uint32_t rl = mt*16u + (lane & 15u);
    if (rl >= realrows){
        v8bf z;
        #pragma unroll
        for (int j = 0; j < 8; ++j) z[j] = (__bf16)0.0f;
        return z;
    }
    return *reinterpret_cast<const v8bf*>(xb + swz128(row0 + rl, kf*64u + ((lane>>4)<<4)));
}

// A-frag from 16-row bf16 buffer (swz256), row = lane&15 (merge/head GEMMs)
__device__ __forceinline__ v8bf ldH(const char* buf, uint32_t kf){
    uint32_t lane = threadIdx.x & 63u;
    return *reinterpret_cast<const v8bf*>(buf + swz256(lane & 15u,
                                          kf*64u + ((lane>>4)<<4)));
}

// A-frag for subtree nl GEMM (node-major): out tile mt -> nodes 2mt,2mt+1;
// children rows 32mt+16*(r>=8)+8*sec+(r&7); u row 16mt+r.
__device__ __forceinline__ v8bf ldA_nl(const char* hprev, const char* ub,
                                       uint32_t mt, uint32_t kf){
    uint32_t lane = threadIdx.x & 63u, r = lane & 15u;
    uint32_t kb = (kf & 3u)*64u + ((lane >> 4) << 4);
    uint32_t sec = kf >> 2;
    if (sec < 2u){
        uint32_t row = mt*32u + ((r >> 3) << 4) + sec*8u + (r & 7u);
        return *reinterpret_cast<const v8bf*>(hprev + swz256(row, kb));
    }
    return *reinterpret_cast<const v8bf*>(ub + swz256(mt*16u + r, kb));
}

// Epilogue: relu(acc+bias) -> bf16 swz256 LDS at rows row0+(l>>4)*4+r, col 16nt+(l&15)
__device__ __forceinline__ void epi(char* dst, uint32_t row0, v4f acc, int nt,
                                    const float* bias){
    uint32_t lane = threadIdx.x & 63u;
    uint32_t col = (uint32_t)nt*16u + (lane & 15u);
    float bv = bias[col];
    uint32_t r0 = row0 + ((lane >> 4) << 2);
    #pragma unroll
    for (int r = 0; r < 4; ++r){
        float v = fmaxf(acc[r] + bv, 0.f);
        *reinterpret_cast<__bf16*>(dst + swz256(r0 + r, col*2u)) = (__bf16)v;
    }
}

// data/leaf GEMM: relu(A @ Wleaf + b), A from bf16 panel, 1 nt per wave
template<int MTN>
__device__ __forceinline__ void gemm_x(const char* xb, uint32_t row0, uint32_t realrows,
                                       char* dst, uint32_t mtB, const v8bf (&wlf)[2],
                                       int nt, const float* bias){
    v4f acc[MTN];
    #pragma unroll
    for (int i = 0; i < MTN; ++i) acc[i] = (v4f){0,0,0,0};
    #pragma unroll
    for (uint32_t kf = 0; kf < 2; ++kf){
        v8bf a[MTN];
        #pragma unroll
        for (int i = 0; i < MTN; ++i) a[i] = ldX(xb, row0, mtB + i, kf, realrows);
        #pragma unroll
        for (int i = 0; i < MTN; ++i) acc[i] = mfma16(a[i], wlf[kf], acc[i]);
    }
    #pragma unroll
    for (int i = 0; i < MTN; ++i) epi(dst, (mtB + i)*16u, acc[i], nt, bias);
}

// nl GEMM: relu([h_even|h_odd|u] @ Wnl + b), node-major, 1 nt per wave
template<int MTN>
__device__ __forceinline__ void gemm_nl(const char* hprev, const char* ub, char* dst,
                                        uint32_t mtB, const v8bf (&wnl)[12],
                                        int nt, const float* bias){
    v4f acc[MTN];
    #pragma unroll
    for (int i = 0; i < MTN; ++i) acc[i] = (v4f){0,0,0,0};
    #pragma unroll
    for (uint32_t kf = 0; kf < 12; ++kf){
        v8bf a[MTN];
        #pragma unroll
        for (int i = 0; i < MTN; ++i) a[i] = ldA_nl(hprev, ub, mtB + i, kf);
        #pragma unroll
        for (int i = 0; i < MTN; ++i) acc[i] = mfma16(a[i], wnl[kf], acc[i]);
    }
    #pragma unroll
    for (int i = 0; i < MTN; ++i) epi(dst, (mtB + i)*16u, acc[i], nt, bias);
}

__global__ __launch_bounds__(NTHR)
__attribute__((amdgpu_waves_per_eu(2, 2)))
void recnn_kernel(const float* __restrict__ Xg,
                  const float* __restrict__ Wleaf, const float* __restrict__ bleaf,
                  const float* __restrict__ Wnl,   const float* __restrict__ bnl,
                  const float* __restrict__ W1g,   const float* __restrict__ b1g,
                  const float* __restrict__ W2g,   const float* __restrict__ b2g,
                  const float* __restrict__ W3g,   const float* __restrict__ b3g,
                  float* __restrict__ Yg)
{
    __shared__ __align__(16) char lds[LDS_BYTES];
    const int t    = threadIdx.x;
    const int wave = t >> 6;
    const int base = blockIdx.x * BC;

    char*  XB   = lds + XB_OFF;
    char*  XB2  = lds + XB2_OFF;
    char*  DB   = lds + DB_OFF;
    char*  DB2  = lds + DB2_OFF;
    char*  HA   = lds + HA_OFF;
    char*  HB   = lds + HB_OFF;
    char*  Ub   = lds + U_OFF;
    char*  HCUR = lds + HCUR_OFF;
    char*  DCUR = lds + DCUR_OFF;
    char*  HSTK = lds + HSTK_OFF;
    char*  DSTK = lds + DSTK_OFF;
    float* BL   = (float*)(lds + BIAS_OFF);
    float* BN   = BL + 128;
    float* B1L  = BL + 256;
    float* B2L  = BL + 384;

    if (t < 128){
        BL[t]  = bleaf[t];
        BN[t]  = bnl[t];
        B1L[t] = b1g[t];
        B2L[t] = b2g[t];
    }

    // Persistent weights: wave owns output cols [16*wave, 16*wave+16) — 56 VGPRs
    const int nt = wave;
    const int n0 = wave << 4;
    v8bf wlf[2], wnl[12];
    #pragma unroll
    for (int kf = 0; kf < 2; ++kf)  wlf[kf] = ldW(Wleaf, kf*32, n0);
    #pragma unroll
    for (int kf = 0; kf < 12; ++kf) wnl[kf] = ldW(Wnl, kf*32, n0);

    // fused pairwise sum: srcF(swz256,node-major) -> dstF f32 + XB2 bf16 mirror
    auto sum_level = [&](char* dstF, uint32_t dRow0, uint32_t xRow0,
                         const char* srcF, uint32_t sRow0, int outrows){
        int total = outrows * 16;
        for (int idx = t; idx < total; idx += NTHR){
            uint32_t row = (uint32_t)(idx >> 4), q = (uint32_t)(idx & 15);
            uint32_t n = row >> 3, b = row & 7u;
            v4f a = *reinterpret_cast<const v4f*>(srcF + swz256(sRow0 + n*16u + b,      q*16u));
            v4f c = *reinterpret_cast<const v4f*>(srcF + swz256(sRow0 + n*16u + 8u + b, q*16u));
            v4f sv = a + c;
            *reinterpret_cast<v4f*>(dstF + swz256(dRow0 + row, q*16u)) = sv;
            *reinterpret_cast<uint2*>(XB2 + swz128(xRow0 + row, q*8u)) = pk4(sv);
        }
    };

    int sp = 0;
    for (int s = 0; s < NSUB; ++s){
        // push previous root
        if (s > 0){
            ((uint2*)(HSTK + sp*4096))[t]    = ((const uint2*)HCUR)[t];
            ((uint32_t*)(DSTK + sp*2048))[t] = ((const uint32_t*)DCUR)[t];
            ++sp;
        }
        // stage: x -> XB bf16; data1 -> DB f32 + XB2[0:64) bf16
        #pragma unroll
        for (int k = 0; k < 2; ++k){
            int idx = t + k*NTHR;                  // 0..1023
            uint32_t rp = (uint32_t)(idx >> 4), q = (uint32_t)(idx & 15);
            uint32_t n = rp >> 3, b = rp & 7u;
            const float* gp = Xg + (size_t)(base + b)*LF + (size_t)(s*16 + 2*n)*FF + q*4;
            v4f xA = *reinterpret_cast<const v4f*>(gp);
            v4f xC = *reinterpret_cast<const v4f*>(gp + FF);
            uint32_t rowA = n*16u + b;
            *reinterpret_cast<uint2*>(XB + swz128(rowA,      q*8u)) = pk4(xA);
            *reinterpret_cast<uint2*>(XB + swz128(rowA + 8u, q*8u)) = pk4(xC);
            v4f sv = xA + xC;
            *reinterpret_cast<v4f*>(DB + swz256(rp, q*16u)) = sv;
            *reinterpret_cast<uint2*>(XB2 + swz128(rp, q*8u)) = pk4(sv);
        }
        __syncthreads();

        // P1: leaf M=128 -> HA ; data2 -> DB2[0:32) + XB2[64:96)
        gemm_x<4>(XB, 0, 128, HA, 0, wlf, nt, BL);
        gemm_x<4>(XB, 0, 128, HA, 4, wlf, nt, BL);
        sum_level(DB2, 0, 64, DB, 0, 32);
        __syncthreads();
        // P2: u1 M=64 -> U ; data3 -> DB[0:16) + XB2[96:112)
        gemm_x<4>(XB2, 0, 64, Ub, 0, wlf, nt, BL);
        sum_level(DB, 0, 96, DB2, 0, 16);
        __syncthreads();
        // P3: nl1 M=64 -> HB ; data4 -> DB2[32:40) + XB2[112:120)
        gemm_nl<4>(HA, Ub, HB, 0, wnl, nt, BN);
        sum_level(DB2, 32, 112, DB, 0, 8);
        __syncthreads();
        // P4: u2 M=32 -> U
        gemm_x<2>(XB2, 64, 32, Ub, 0, wlf, nt, BL);
        __syncthreads();
        // P5: nl2 M=32 -> HA[0:32)
        gemm_nl<2>(HB, Ub, HA, 0, wnl, nt, BN);
        __syncthreads();
        // P6: u3 M=16 -> U
        gemm_x<1>(XB2, 96, 16, Ub, 0, wlf, nt, BL);
        __syncthreads();
        // P7: nl3 M=16 -> HB[0:16)
        gemm_nl<1>(HA, Ub, HB, 0, wnl, nt, BN);
        __syncthreads();
        // P8: u4 M=8 -> U
        gemm_x<1>(XB2, 112, 8, Ub, 0, wlf, nt, BL);
        __syncthreads();
        // P9: nl4 -> HCUR ; copy data4 f32 -> DCUR
        gemm_nl<1>(HB, Ub, HCUR, 0, wnl, nt, BN);
        {
            uint32_t row = (uint32_t)(t >> 6), f = (uint32_t)(t & 63);
            *reinterpret_cast<float*>(DCUR + swz256(row, f*4u)) =
                *reinterpret_cast<const float*>(DB2 + swz256(32u + row, f*4u));
        }
        __syncthreads();

        // DFS merges among subtree roots (M=8 padded to 16)
        int nm = __builtin_ctz(s + 1);
        for (int m = 0; m < nm; ++m){
            --sp;
            const char* hl = HSTK + sp*4096;
            {   // root data sum + bf16 mirror -> XB2[120:128)
                uint32_t row = (uint32_t)(t >> 6), f = (uint32_t)(t & 63);
                float v = *reinterpret_cast<const float*>(DCUR + swz256(row, f*4u))
                        + *reinterpret_cast<const float*>(DSTK + sp*2048 + swz256(row, f*4u));
                *reinterpret_cast<float*>(DCUR + swz256(row, f*4u)) = v;
                *reinterpret_cast<__bf16*>(XB2 + swz128(120u + row, f*2u)) = (__bf16)v;
            }
            __syncthreads();
            gemm_x<1>(XB2, 120, 8, Ub, 0, wlf, nt, BL);
            __syncthreads();
            v4f c = (v4f){0,0,0,0};
            #pragma unroll
            for (uint32_t kf = 0; kf < 12; ++kf){
                const char* src = (kf < 4) ? hl : ((kf < 8) ? (const char*)HCUR
                                                            : (const char*)Ub);
                c = mfma16(ldH(src, kf & 3u), wnl[kf], c);
            }
            __syncthreads();   // reads of HCUR done before in-place write
            epi(HCUR, 0, c, nt, BN);
            __syncthreads();
        }
    }

    // ---- head: z1 = relu(enc@W1+b1) -> U; z2 -> HB; out = z2@W3+b3 ----
    {
        v8bf w1f[4], w2f[4];
        #pragma unroll
        for (int kf = 0; kf < 4; ++kf){
            w1f[kf] = ldW(W1g, kf*32, n0);
            w2f[kf] = ldW(W2g, kf*32, n0);
        }
        {
            v4f c = (v4f){0,0,0,0};
            #pragma unroll
            for (uint32_t kf = 0; kf < 4; ++kf) c = mfma16(ldH(HCUR, kf), w1f[kf], c);
            epi(Ub, 0, c, nt, B1L);
        }
        __syncthreads();
        {
            v4f c = (v4f){0,0,0,0};
            #pragma unroll
            for (uint32_t kf = 0; kf < 4; ++kf) c = mfma16(ldH(Ub, kf), w2f[kf], c);
            epi(HB, 0, c, nt, B2L);
        }
        __syncthreads();
        if (t < 64){
            float w3a = W3g[t], w3b = W3g[t + 64], b3v = b3g[0];
            #pragma unroll
            for (int r = 0; r < 8; ++r){
                float za = (float)*reinterpret_cast<const __bf16*>(HB + swz256((uint32_t)r, (uint32_t)t*2u));
                float zb = (float)*reinterpret_cast<const __bf16*>(HB + swz256((uint32_t)r, (uint32_t)(t + 64)*2u));
                float v = za*w3a + zb*w3b;
                #pragma unroll
                for (int off = 32; off >= 1; off >>= 1) v += __shfl_xor(v, off, 64);
                if (t == 0) Yg[base + r] = v + b3v;
            }
        }
    }
}

extern "C" void kernel_launch(void* const* d_in, const int* in_sizes, int n_in,
                              void* d_out, int out_size, void* d_ws, size_t ws_size,
                              hipStream_t stream){
    const float* x     = (const float*)d_in[0];
    const float* Wleaf = (const float*)d_in[1];
    const float* bleaf = (const float*)d_in[2];
    const float* Wnl   = (const float*)d_in[3];
    const float* bnl   = (const float*)d_in[4];
    const float* W1    = (const float*)d_in[5];
    const float* b1    = (const float*)d_in[6];
    const float* W2    = (const float*)d_in[7];
    const float* b2    = (const float*)d_in[8];
    const float* W3    = (const float*)d_in[9];
    const float* b3    = (const float*)d_in[10];
    float* out = (float*)d_out;

    recnn_kernel<<<B_TOT/BC, NTHR, 0, stream>>>(x, Wleaf, bleaf, Wnl, bnl,
                                                W1, b1, W2, b2, W3, b3, out);
}